// Round 8
// baseline (265.646 us; speedup 1.0000x reference)
//
#include <hip/hip_runtime.h>

#define Bn 4
#define Cn 32
#define Hn 320
#define Wn 320
#define NCn 21
#define HWSZ (Hn*Wn)

#define TH 16              // tile rows
#define TW 32              // tile cols
#define HH 22              // TH+6 halo rows
#define HCOL 38            // TW+6 valid halo cols
#define FW 40              // F row stride in words (even -> 8B-aligned b64 reads)
#define NG 8               // 8 groups of 4 fp8 channels per 32-bit word
#define QSTR 40            // Q row stride in bytes

typedef _Float16 h2 __attribute__((ext_vector_type(2)));

#define LDS_F   (NG*HH*FW*4)                  // 28160 B
#define LDS_Q   (NCn*HH*QSTR)                 // 18480 B
#define LDS_TOTAL (LDS_F + LDS_Q)             // 46640 B -> 3 blocks/CU

// exact fp8(e4m3) pair -> f16 pair scaled by 2^-8 (handles denormals exactly)
__device__ __forceinline__ h2 fp8pair_lo(uint32_t w) {
  uint32_t t = ((w & 0x000000FFu) << 8) | ((w & 0x0000FF00u) << 16);
  uint32_t r = (t & 0x80008000u) | ((t >> 1) & 0x3FFF3FFFu);
  return __builtin_bit_cast(h2, r);
}
__device__ __forceinline__ h2 fp8pair_hi(uint32_t w) {
  uint32_t t = ((w >> 8) & 0x0000FF00u) | (w & 0xFF000000u);
  uint32_t r = (t & 0x80008000u) | ((t >> 1) & 0x3FFF3FFFu);
  return __builtin_bit_cast(h2, r);
}

__device__ __forceinline__ float fdot2f(h2 a, h2 b, float c) {
#if __has_builtin(__builtin_amdgcn_fdot2)
  return __builtin_amdgcn_fdot2(a, b, c, false);
#else
  return c + (float)a[0]*(float)b[0] + (float)a[1]*(float)b[1];
#endif
}

// 2 px/thread: live set ~115 VGPR -> fits the 170 budget of (256,3) w/o spill.
__global__ __launch_bounds__(256, 3) void crf_fused3(
    const float* __restrict__ Fin, const float* __restrict__ logit,
    const float* __restrict__ weight, const float* __restrict__ compat,
    const float* __restrict__ bias, float* __restrict__ out)
{
  extern __shared__ char smem[];
  uint32_t* fbuf = (uint32_t*)smem;                // [NG][HH][FW] fp8x4 words
  uint8_t*  qbuf = (uint8_t*)(smem + LDS_F);       // [NCn][HH][QSTR] fp8

  const int bid = blockIdx.x;
  const int b   = bid / 200;
  const int r   = bid % 200;
  const int th  = r / 10, twi = r % 10;
  const int h0  = th * TH, w0 = twi * TW;
  const int tid = threadIdx.x;

  // ---------------- stage F: fp32 -> fp8x4 words ---------------------------------
  const float* fb0 = Fin + (size_t)b * Cn * HWSZ;
  for (int idx = tid; idx < NG * HH * FW; idx += 256) {
    int lw = idx % FW;
    int r2 = idx / FW;
    int lh = r2 % HH;
    int g  = r2 / HH;
    int gh = h0 - 3 + lh, gw = w0 - 3 + lw;
    uint32_t wd = 0u;
    if (lw < HCOL && (unsigned)gh < (unsigned)Hn && (unsigned)gw < (unsigned)Wn) {
      const float* p = fb0 + (size_t)(4 * g) * HWSZ + gh * Wn + gw;
      float f0 = p[0], f1 = p[HWSZ], f2 = p[2 * HWSZ], f3 = p[3 * HWSZ];
      int pk = __builtin_amdgcn_cvt_pk_fp8_f32(f0, f1, 0, false);
      pk = __builtin_amdgcn_cvt_pk_fp8_f32(f2, f3, pk, true);
      wd = (uint32_t)pk;
    }
    fbuf[idx] = wd;
  }

  // ---------------- stage Q = softmax(logit) as fp8 -------------------------------
  const float* lg0 = logit + (size_t)b * NCn * HWSZ;
  for (int p = tid; p < HH * HCOL; p += 256) {
    int lw = p % HCOL, lh = p / HCOL;
    int gh = h0 - 3 + lh, gw = w0 - 3 + lw;
    uint8_t* qp = qbuf + lh * QSTR + lw;
    if ((unsigned)gh < (unsigned)Hn && (unsigned)gw < (unsigned)Wn) {
      const float* lp = lg0 + gh * Wn + gw;
      float v[NCn];
      float m = -1e30f;
      #pragma unroll
      for (int o = 0; o < NCn; o++) { v[o] = lp[(size_t)o * HWSZ]; m = fmaxf(m, v[o]); }
      float s = 0.f;
      #pragma unroll
      for (int o = 0; o < NCn; o++) { v[o] = __expf(v[o] - m); s += v[o]; }
      float inv = 1.0f / s;
      #pragma unroll
      for (int o = 0; o < NCn; o++) {
        int pk = __builtin_amdgcn_cvt_pk_fp8_f32(v[o] * inv, 0.f, 0, false);
        qp[(size_t)o * HH * QSTR] = (uint8_t)(pk & 0xff);
      }
    } else {
      #pragma unroll
      for (int o = 0; o < NCn; o++) qp[(size_t)o * HH * QSTR] = 0;
    }
  }
  __syncthreads();

  // ---------------- main: 2 px/thread, 16 rows x 16 col-groups --------------------
  const int ty = tid >> 4;        // tile row 0..15
  const int tg = tid & 15;        // col group: px cols 2tg, 2tg+1
  const int x2 = tg << 1;         // first px tile-col

  // centers: px p at halo col x2+p+3 -> decoded h2 pairs (f16 * 2^-8)
  h2 cen[NG][4];
  #pragma unroll
  for (int g = 0; g < NG; g++) {
    const uint32_t* fc = fbuf + (g * HH + (ty + 3)) * FW + (x2 + 3);
    #pragma unroll
    for (int p = 0; p < 2; p++) {
      uint32_t w = fc[p];
      cen[g][2 * p]     = fp8pair_lo(w);
      cen[g][2 * p + 1] = fp8pair_hi(w);
    }
  }

  float acc[2][NCn];
  #pragma unroll
  for (int p = 0; p < 2; p++)
    #pragma unroll
    for (int o = 0; o < NCn; o++) acc[p][o] = 0.f;

  // Q neighbor alignment: bytes x2 .. x2+7 within row; t = x2 & 3
  const int qw0 = x2 >> 2;
  const int qsh = (x2 & 3) * 8;

  #pragma unroll 1
  for (int di = 0; di < 7; di++) {
    const int lhn = ty + di;
    float ds[2][7];
    #pragma unroll
    for (int p = 0; p < 2; p++)
      #pragma unroll
      for (int j = 0; j < 7; j++) ds[p][j] = 0.f;

    #pragma unroll
    for (int g = 0; g < NG; g++) {
      const uint2* frow = (const uint2*)(fbuf + (g * HH + lhn) * FW + x2);
      uint2 a = frow[0], bb = frow[1], c = frow[2], d = frow[3];
      uint32_t nw[8] = {a.x, a.y, bb.x, bb.y, c.x, c.y, d.x, d.y};
      h2 nlo[8], nhi[8];
      #pragma unroll
      for (int k = 0; k < 8; k++) { nlo[k] = fp8pair_lo(nw[k]); nhi[k] = fp8pair_hi(nw[k]); }
      #pragma unroll
      for (int p = 0; p < 2; p++) {
        #pragma unroll
        for (int j = 0; j < 7; j++) {
          h2 d0 = cen[g][2 * p]     - nlo[p + j];
          h2 d1 = cen[g][2 * p + 1] - nhi[p + j];
          float t = fdot2f(d0, d0, ds[p][j]);
          ds[p][j] = fdot2f(d1, d1, t);
        }
      }
    }

    // kern = exp(-diff/C); ds carries 2^-16 scale -> multiplier -2048 = -(2^16/32)
    #pragma unroll
    for (int p = 0; p < 2; p++)
      #pragma unroll
      for (int j = 0; j < 7; j++)
        ds[p][j] = __expf(ds[p][j] * -2048.0f);

    #pragma unroll
    for (int o = 0; o < NCn; o++) {
      const uint32_t* qrow = (const uint32_t*)(qbuf + (o * HH + lhn) * QSTR) + qw0;
      uint32_t q0 = qrow[0], q1 = qrow[1], q2 = qrow[2];
      // byte-align: 8 bytes starting at byte (x2&3) of [q0,q1,q2]
      uint32_t a0 = (uint32_t)(((((uint64_t)q1 << 32) | q0)) >> qsh);
      uint32_t a1 = (uint32_t)(((((uint64_t)q2 << 32) | q1)) >> qsh);
      float qv[8];
      qv[0] = __builtin_amdgcn_cvt_f32_fp8((int)a0, 0);
      qv[1] = __builtin_amdgcn_cvt_f32_fp8((int)a0, 1);
      qv[2] = __builtin_amdgcn_cvt_f32_fp8((int)a0, 2);
      qv[3] = __builtin_amdgcn_cvt_f32_fp8((int)a0, 3);
      qv[4] = __builtin_amdgcn_cvt_f32_fp8((int)a1, 0);
      qv[5] = __builtin_amdgcn_cvt_f32_fp8((int)a1, 1);
      qv[6] = __builtin_amdgcn_cvt_f32_fp8((int)a1, 2);
      qv[7] = __builtin_amdgcn_cvt_f32_fp8((int)a1, 3);
      #pragma unroll
      for (int p = 0; p < 2; p++)
        #pragma unroll
        for (int j = 0; j < 7; j++)
          acc[p][o] = fmaf(ds[p][j], qv[p + j], acc[p][o]);
    }
  }

  // ---------------- epilogue: compat mix + bias + logit subtract ------------------
  __syncthreads();
  float* cmat = (float*)smem;     // reuse F area: 441 floats
  {
    float wgt = weight[0] * (1.0f / 7.0f);
    for (int i = tid; i < NCn * NCn; i += 256) {
      float c = compat[i];
      cmat[i] = wgt / (1.f + __expf(-c));  // sigmoid * weight / kernel_len
    }
  }
  __syncthreads();

  const int gh = h0 + ty;
  const size_t pixoff = (size_t)b * NCn * HWSZ + (size_t)gh * Wn + (w0 + x2);
  const float* lc = logit + pixoff;
  float* oc = out + pixoff;
  #pragma unroll
  for (int o = 0; o < NCn; o++) {
    float s0 = 0.f, s1 = 0.f;
    #pragma unroll
    for (int i2 = 0; i2 < NCn; i2++) {
      float cm = cmat[o * NCn + i2];
      s0 = fmaf(cm, acc[0][i2], s0);
      s1 = fmaf(cm, acc[1][i2], s1);
    }
    float bo = bias[o];
    const float2 lg = *(const float2*)(lc + (size_t)o * HWSZ);
    float2 rr;
    rr.x = lg.x - s0 - bo;
    rr.y = lg.y - s1 - bo;
    *(float2*)(oc + (size_t)o * HWSZ) = rr;
  }
}

extern "C" void kernel_launch(void* const* d_in, const int* in_sizes, int n_in,
                              void* d_out, int out_size, void* d_ws, size_t ws_size,
                              hipStream_t stream) {
  (void)in_sizes; (void)n_in; (void)out_size; (void)d_ws; (void)ws_size;
  const float* F      = (const float*)d_in[0];
  const float* logit  = (const float*)d_in[1];
  const float* weight = (const float*)d_in[2];
  const float* compat = (const float*)d_in[3];
  const float* bias   = (const float*)d_in[4];
  float* out = (float*)d_out;

  hipFuncSetAttribute((const void*)crf_fused3,
                      hipFuncAttributeMaxDynamicSharedMemorySize, LDS_TOTAL);
  crf_fused3<<<dim3(Bn * 200), dim3(256), LDS_TOTAL, stream>>>(
      F, logit, weight, compat, bias, out);
}